// Round 4
// baseline (28340.552 us; speedup 1.0000x reference)
//
#include <hip/hip_runtime.h>
#include <math.h>

// Problem constants
#define BB 16
#define TT 128
#define F_IN 240
#define E_DIM 1024
#define HH 320
#define G4 1280        // 4*H
#define JHD 512
#define VV 29
#define BLANKV 28
#define MAXSYM 3
#define LBUF (TT*MAXSYM) // 384

#define NB 32          // persistent grid blocks (all co-resident; 1 per CU)
#define SBUF 5120      // per-state-buffer stride (16*320)
#define HPITCH 328     // padded LDS row pitch for h vectors (floats)

// Workspace layout (float offsets)
#define OFF_FPROJ  0ul                         // 2048*512 = 1048576
#define OFF_WJHR   1048576ul                   // 512*320 row-major (j,k)
#define OFF_EP     (OFF_WJHR + 163840ul)       // 29*1280
#define OFF_B1     (OFF_EP + 37120ul)          // 1280
#define OFF_H0     (OFF_B1 + 1280ul)           // 2*16*320
#define OFF_H1     (OFF_H0 + 10240ul)          // 2*16*320
#define OFF_PLOG   (OFF_H1 + 10240ul)          // 32*464
#define OFF_SYNC   (OFF_PLOG + 14848ul)        // ints: count@0, release@32

__device__ __forceinline__ float sigmoidf_(float x) {
    return 1.0f / (1.0f + expf(-x));
}
__device__ __forceinline__ float ld_agent(const float* p) {
    return __hip_atomic_load(p, __ATOMIC_RELAXED, __HIP_MEMORY_SCOPE_AGENT);
}
__device__ __forceinline__ void st_agent(float* p, float v) {
    __hip_atomic_store(p, v, __ATOMIC_RELAXED, __HIP_MEMORY_SCOPE_AGENT);
}

// ---- Prep: WjhR[j][k] = Wj1[1024+k][j]; b1 = bih1 + bhh1 ----
__global__ void prep_t_kernel(const float* __restrict__ Wj1,
                              const float* __restrict__ bih1,
                              const float* __restrict__ bhh1,
                              float* __restrict__ WjhR, float* __restrict__ b1) {
    int idx = blockIdx.x * 256 + threadIdx.x;
    if (idx < 163840) {
        int j = idx / 320, k = idx - j * 320;
        WjhR[idx] = Wj1[(size_t)(1024 + k) * JHD + j];
        return;
    }
    int i2 = idx - 163840;
    if (i2 < G4) b1[i2] = bih1[i2] + bhh1[i2];
}

// ---- Prep: EP[v][j] = embed[v] @ Wih0[j,:] + bih0[j] + bhh0[j]; row 28 = bias only
__global__ void ep_kernel(const float* __restrict__ embed,
                          const float* __restrict__ Wih0,
                          const float* __restrict__ bih0,
                          const float* __restrict__ bhh0,
                          float* __restrict__ EP) {
    __shared__ __align__(16) float es[HH];
    int v = blockIdx.x;
    for (int k = threadIdx.x; k < HH; k += 256)
        es[k] = (v < VV - 1) ? embed[v * HH + k] : 0.0f;
    __syncthreads();
    for (int j = threadIdx.x; j < G4; j += 256) {
        float acc = bih0[j] + bhh0[j];
        if (v < VV - 1) {
            const float4* wr = (const float4*)(Wih0 + (size_t)j * HH);
            const float4* ev = (const float4*)es;
            #pragma unroll 4
            for (int k4 = 0; k4 < HH / 4; ++k4) {
                float4 w = wr[k4], e = ev[k4];
                acc += w.x * e.x + w.y * e.y + w.z * e.z + w.w * e.w;
            }
        }
        EP[v * G4 + j] = acc;
    }
}

// ---- Encoder + F_proj fused ----
__global__ __launch_bounds__(512) void enc_fproj_kernel(
    const float* __restrict__ x, const float* __restrict__ Wenc,
    const float* __restrict__ benc, const float* __restrict__ Wj1,
    const float* __restrict__ bj1,
    float* __restrict__ logits_out, float* __restrict__ Fproj) {
    __shared__ float xs[8][F_IN];
    __shared__ float ls[8][E_DIM];
    int row0 = blockIdx.x * 8;
    int tid = threadIdx.x;
    for (int i = tid; i < 8 * F_IN; i += 512)
        xs[i / F_IN][i % F_IN] = x[(size_t)row0 * F_IN + i];
    __syncthreads();
    for (int j = tid; j < E_DIM; j += 512) {
        float acc[8];
        float bv = benc[j];
        #pragma unroll
        for (int r = 0; r < 8; ++r) acc[r] = bv;
        for (int k = 0; k < F_IN; ++k) {
            float w = Wenc[(size_t)k * E_DIM + j];
            #pragma unroll
            for (int r = 0; r < 8; ++r) acc[r] += xs[r][k] * w;
        }
        #pragma unroll
        for (int r = 0; r < 8; ++r) {
            ls[r][j] = acc[r];
            logits_out[(size_t)(row0 + r) * E_DIM + j] = acc[r];
        }
    }
    __syncthreads();
    {
        int j = tid;
        float acc[8];
        float bv = bj1[j];
        #pragma unroll
        for (int r = 0; r < 8; ++r) acc[r] = bv;
        for (int k = 0; k < E_DIM; ++k) {
            float w = Wj1[(size_t)k * JHD + j];
            #pragma unroll
            for (int r = 0; r < 8; ++r) acc[r] += ls[r][k] * w;
        }
        #pragma unroll
        for (int r = 0; r < 8; ++r) Fproj[(size_t)(row0 + r) * JHD + j] = acc[r];
    }
}

// ---- Init: zero state + sync words; labels=-1; out_lens passthrough ----
__global__ void init_kernel(const int* __restrict__ lens, float* ws,
                            float* __restrict__ out_lens_out,
                            float* __restrict__ labels_out) {
    int tid = threadIdx.x;
    float* h0 = ws + OFF_H0;
    for (int i = tid; i < 20480; i += 1024) h0[i] = 0.0f;   // H0 + H1, both buffers
    int* sync = (int*)(ws + OFF_SYNC);
    if (tid < 64) sync[tid] = 0;
    for (int i = tid; i < BB * LBUF; i += 1024) labels_out[i] = -1.0f;
    if (tid < BB) out_lens_out[tid] = (float)lens[tid];
}

// ---- Central-counter barrier with single release word ----
// Arrive: one atomicAdd per block. Wait: spin on ONE word (same addr for all
// pollers -> one 64B LLC line per poll, no line storm).
__device__ __forceinline__ void gbar(int* cnt, int* rel, int e) {
    asm volatile("s_waitcnt vmcnt(0)" ::: "memory");  // drain sc1 data stores
    __syncthreads();
    if (threadIdx.x == 0) {
        int old = __hip_atomic_fetch_add(cnt, 1, __ATOMIC_RELAXED,
                                         __HIP_MEMORY_SCOPE_AGENT);
        if (old == e * NB - 1) {
            __hip_atomic_store(rel, e, __ATOMIC_RELAXED, __HIP_MEMORY_SCOPE_AGENT);
        } else {
            while (__hip_atomic_load(rel, __ATOMIC_RELAXED,
                                     __HIP_MEMORY_SCOPE_AGENT) < e)
                __builtin_amdgcn_s_sleep(1);
        }
    }
    asm volatile("" ::: "memory");
    __syncthreads();
}

// ---- Persistent lockstep decoder: 32 blocks x 1024 threads, 3 barriers/slot ----
__global__ __launch_bounds__(1024) void decode_persistent(
    const int* __restrict__ lens,
    const float* __restrict__ Fproj,
    const float* __restrict__ W0,    // Whh0 [1280][320]
    const float* __restrict__ W1a,   // Wih1 [1280][320]
    const float* __restrict__ W1b,   // Whh1 [1280][320]
    const float* __restrict__ WjhR,  // [512][320]
    const float* __restrict__ Wj2,   // [512][29]
    const float* __restrict__ EP, const float* __restrict__ b1,
    const float* __restrict__ bj2,
    float* H0, float* H1, float* plog, int* syncw,
    float* __restrict__ labels_out, float* __restrict__ counts_out) {

    const int tid = threadIdx.x;
    const int blk = blockIdx.x;
    int* cnt = syncw;
    int* rel = syncw + 32;

    __shared__ __align__(16) float sh_a[16 * HPITCH];
    __shared__ __align__(16) float sh_b[16 * HPITCH];
    __shared__ float sh_g[40 * 17];
    __shared__ float sh_lg[16 * 30];
    __shared__ int curL[16], lastL[16], contL[16], cntL[16], lenL[16];
    __shared__ int sMaxL;

    if (tid < 16) {
        curL[tid] = 0; lastL[tid] = BLANKV; contL[tid] = 0; cntL[tid] = 0;
        lenL[tid] = lens[tid];
    }
    if (tid == 0) {
        int m = 0;
        for (int i = 0; i < BB; ++i) m = max(m, lens[i]);
        sMaxL = m;
    }
    __syncthreads();
    const int maxL = sMaxL;

    // lane decomposition: b_lo(2b) kc(4b) bh(2b) jg(2b)
    const int b_lo = tid & 3;
    const int kc   = (tid >> 2) & 15;
    const int bh   = (tid >> 6) & 3;
    const int jg   = tid >> 8;             // gate group (A/B) / j-group (C)
    const int b    = (bh << 2) | b_lo;
    const int kf   = kc * 20;

    // update threads: tid<160 -> (b=tid&15, il=tid>>4 in 0..9)
    const int ub = tid & 15, il = tid >> 4;
    float c0A = 0.f, c0B = 0.f, c1A = 0.f, c1B = 0.f;

    int epoch = 0;

    for (int slot = 0; slot < 3 * maxL; ++slot) {
        const int t = slot / 3;
        const int s = slot - t * 3;

        // ========== Phase A: LSTM cell 0 (block owns 40 gate rows) ==========
        for (int idx = tid; idx < SBUF; idx += 1024) {
            int ib = idx / 320, k = idx - ib * 320;
            sh_a[ib * HPITCH + k] = ld_agent(H0 + curL[ib] * SBUF + idx);
        }
        __syncthreads();
        {
            const float4* hv = (const float4*)(sh_a + b * HPITCH + kf);
            const float*  w0 = W0 + (size_t)(jg * 320 + blk * 10) * 320 + kf;
            float acc[10] = {0.f,0.f,0.f,0.f,0.f,0.f,0.f,0.f,0.f,0.f};
            #pragma unroll
            for (int q = 0; q < 5; ++q) {
                float4 h = hv[q];
                #pragma unroll
                for (int jj = 0; jj < 10; ++jj) {
                    float4 w = *(const float4*)(w0 + jj * 320 + q * 4);
                    acc[jj] += h.x * w.x + h.y * w.y + h.z * w.z + h.w * w.w;
                }
            }
            #pragma unroll
            for (int jj = 0; jj < 10; ++jj) {
                float a = acc[jj];
                a += __shfl_xor(a, 4);  a += __shfl_xor(a, 8);
                a += __shfl_xor(a, 16); a += __shfl_xor(a, 32);
                acc[jj] = a;
            }
            if (kc == 0) {
                const float* ep = EP + (size_t)lastL[b] * G4 + jg * 320 + blk * 10;
                #pragma unroll
                for (int jj = 0; jj < 10; ++jj)
                    sh_g[(jg * 10 + jj) * 17 + b] = acc[jj] + ep[jj];
            }
        }
        __syncthreads();
        if (tid < 160) {
            int cb = curL[ub];
            int i  = blk * 10 + il;
            float xi = sh_g[(0 * 10 + il) * 17 + ub];
            float xf = sh_g[(1 * 10 + il) * 17 + ub];
            float xg = sh_g[(2 * 10 + il) * 17 + ub];
            float xo = sh_g[(3 * 10 + il) * 17 + ub];
            float cold = cb ? c0B : c0A;
            float c = sigmoidf_(xf) * cold + sigmoidf_(xi) * tanhf(xg);
            if (cb) c0A = c; else c0B = c;      // write pend slot
            st_agent(H0 + (cb ^ 1) * SBUF + ub * 320 + i, sigmoidf_(xo) * tanhf(c));
        }
        gbar(cnt, rel, ++epoch);

        // ========== Phase B: LSTM cell 1 ==========
        for (int idx = tid; idx < SBUF; idx += 1024) {
            int ib = idx / 320, k = idx - ib * 320;
            sh_a[ib * HPITCH + k] = ld_agent(H0 + (curL[ib] ^ 1) * SBUF + idx);
        }
        for (int idx = tid; idx < SBUF; idx += 1024) {
            int ib = idx / 320, k = idx - ib * 320;
            sh_b[ib * HPITCH + k] = ld_agent(H1 + curL[ib] * SBUF + idx);
        }
        __syncthreads();
        {
            const float4* ha = (const float4*)(sh_a + b * HPITCH + kf);
            const float4* hb = (const float4*)(sh_b + b * HPITCH + kf);
            const float*  wa = W1a + (size_t)(jg * 320 + blk * 10) * 320 + kf;
            const float*  wb = W1b + (size_t)(jg * 320 + blk * 10) * 320 + kf;
            float acc[10] = {0.f,0.f,0.f,0.f,0.f,0.f,0.f,0.f,0.f,0.f};
            #pragma unroll
            for (int q = 0; q < 5; ++q) {
                float4 x = ha[q], y = hb[q];
                #pragma unroll
                for (int jj = 0; jj < 10; ++jj) {
                    float4 w1 = *(const float4*)(wa + jj * 320 + q * 4);
                    float4 w2 = *(const float4*)(wb + jj * 320 + q * 4);
                    acc[jj] += x.x * w1.x + x.y * w1.y + x.z * w1.z + x.w * w1.w
                             + y.x * w2.x + y.y * w2.y + y.z * w2.z + y.w * w2.w;
                }
            }
            #pragma unroll
            for (int jj = 0; jj < 10; ++jj) {
                float a = acc[jj];
                a += __shfl_xor(a, 4);  a += __shfl_xor(a, 8);
                a += __shfl_xor(a, 16); a += __shfl_xor(a, 32);
                acc[jj] = a;
            }
            if (kc == 0) {
                const float* bb1 = b1 + jg * 320 + blk * 10;
                #pragma unroll
                for (int jj = 0; jj < 10; ++jj)
                    sh_g[(jg * 10 + jj) * 17 + b] = acc[jj] + bb1[jj];
            }
        }
        __syncthreads();
        if (tid < 160) {
            int cb = curL[ub];
            int i  = blk * 10 + il;
            float xi = sh_g[(0 * 10 + il) * 17 + ub];
            float xf = sh_g[(1 * 10 + il) * 17 + ub];
            float xg = sh_g[(2 * 10 + il) * 17 + ub];
            float xo = sh_g[(3 * 10 + il) * 17 + ub];
            float cold = cb ? c1B : c1A;
            float c = sigmoidf_(xf) * cold + sigmoidf_(xi) * tanhf(xg);
            if (cb) c1A = c; else c1B = c;
            st_agent(H1 + (cb ^ 1) * SBUF + ub * 320 + i, sigmoidf_(xo) * tanhf(c));
        }
        gbar(cnt, rel, ++epoch);

        // ========== Phase C: jh j-slice + partial logits (all 32 blocks) ==========
        {
            for (int idx = tid; idx < SBUF; idx += 1024) {
                int ib = idx / 320, k = idx - ib * 320;
                sh_a[ib * HPITCH + k] = ld_agent(H1 + (curL[ib] ^ 1) * SBUF + idx);
            }
            __syncthreads();
            {
                const float4* hv = (const float4*)(sh_a + b * HPITCH + kf);
                const float*  wc = WjhR + (size_t)(blk * 16 + jg * 4) * 320 + kf;
                float acc[4] = {0.f,0.f,0.f,0.f};
                #pragma unroll
                for (int q = 0; q < 5; ++q) {
                    float4 h = hv[q];
                    #pragma unroll
                    for (int jj = 0; jj < 4; ++jj) {
                        float4 w = *(const float4*)(wc + jj * 320 + q * 4);
                        acc[jj] += h.x * w.x + h.y * w.y + h.z * w.z + h.w * w.w;
                    }
                }
                #pragma unroll
                for (int jj = 0; jj < 4; ++jj) {
                    float a = acc[jj];
                    a += __shfl_xor(a, 4);  a += __shfl_xor(a, 8);
                    a += __shfl_xor(a, 16); a += __shfl_xor(a, 32);
                    acc[jj] = a;
                }
                if (kc == 0) {
                    const float* fp = Fproj + ((size_t)b * TT + t) * JHD + blk * 16 + jg * 4;
                    #pragma unroll
                    for (int jj = 0; jj < 4; ++jj)
                        sh_g[(jg * 4 + jj) * 17 + b] = fmaxf(fp[jj] + acc[jj], 0.f);
                }
            }
            __syncthreads();
            if (tid < 464) {
                int b2 = tid / 29, v = tid - b2 * 29;
                float p = 0.f;
                #pragma unroll
                for (int jl = 0; jl < 16; ++jl)
                    p += sh_g[jl * 17 + b2] * Wj2[(size_t)(blk * 16 + jl) * VV + v];
                st_agent(plog + blk * 464 + tid, p);
            }
        }
        gbar(cnt, rel, ++epoch);

        // ========== Phase D: reduce partials + argmax + commit (replicated) ==========
        if (tid < 464) {
            int b2 = tid / 29, v = tid - b2 * 29;
            float acc = bj2[v];
            #pragma unroll
            for (int r = 0; r < 32; ++r)
                acc += ld_agent(plog + r * 464 + tid);
            sh_lg[b2 * 30 + v] = acc;
        }
        __syncthreads();
        if (tid < 16) {
            float best = sh_lg[tid * 30];
            int k = 0;
            #pragma unroll
            for (int v = 1; v < VV; ++v) {
                float x = sh_lg[tid * 30 + v];
                if (x > best) { best = x; k = v; }
            }
            bool active = (t < lenL[tid]) && (s == 0 || contL[tid]);
            bool emit = active && (k != BLANKV);
            if (emit) {
                if (blk == 0)
                    labels_out[(size_t)tid * LBUF + cntL[tid]] = (float)k;
                cntL[tid]++; lastL[tid] = k; curL[tid] ^= 1; contL[tid] = 1;
            } else {
                contL[tid] = 0;
            }
        }
        __syncthreads();
    }

    if (blk == 0 && tid < 16) counts_out[tid] = (float)cntL[tid];
}

extern "C" void kernel_launch(void* const* d_in, const int* in_sizes, int n_in,
                              void* d_out, int out_size, void* d_ws, size_t ws_size,
                              hipStream_t stream) {
    const float* x      = (const float*)d_in[0];
    const int*   lens   = (const int*)d_in[1];
    const float* Wenc   = (const float*)d_in[2];
    const float* benc   = (const float*)d_in[3];
    const float* embed  = (const float*)d_in[4];
    const float* Wih0   = (const float*)d_in[5];
    const float* Whh0   = (const float*)d_in[6];
    const float* bih0   = (const float*)d_in[7];
    const float* bhh0   = (const float*)d_in[8];
    const float* Wih1   = (const float*)d_in[9];
    const float* Whh1   = (const float*)d_in[10];
    const float* bih1   = (const float*)d_in[11];
    const float* bhh1   = (const float*)d_in[12];
    const float* Wj1    = (const float*)d_in[13];
    const float* bj1    = (const float*)d_in[14];
    const float* Wj2    = (const float*)d_in[15];
    const float* bj2    = (const float*)d_in[16];

    float* out = (float*)d_out;
    float* logits_out   = out;
    float* out_lens_out = out + (size_t)BB * TT * E_DIM;
    float* labels_out   = out_lens_out + BB;
    float* counts_out   = labels_out + (size_t)BB * LBUF;

    float* ws    = (float*)d_ws;
    float* Fproj = ws + OFF_FPROJ;
    float* WjhR  = ws + OFF_WJHR;
    float* EP    = ws + OFF_EP;
    float* b1    = ws + OFF_B1;
    float* H0    = ws + OFF_H0;
    float* H1    = ws + OFF_H1;
    float* plog  = ws + OFF_PLOG;
    int*   syncw = (int*)(ws + OFF_SYNC);

    {
        int total = 163840 + G4;
        prep_t_kernel<<<(total + 255) / 256, 256, 0, stream>>>(Wj1, bih1, bhh1, WjhR, b1);
    }
    ep_kernel<<<VV, 256, 0, stream>>>(embed, Wih0, bih0, bhh0, EP);
    enc_fproj_kernel<<<(BB * TT) / 8, 512, 0, stream>>>(x, Wenc, benc, Wj1, bj1,
                                                        logits_out, Fproj);
    init_kernel<<<1, 1024, 0, stream>>>(lens, ws, out_lens_out, labels_out);
    decode_persistent<<<NB, 1024, 0, stream>>>(lens, Fproj, Whh0, Wih1, Whh1,
                                               WjhR, Wj2, EP, b1, bj2,
                                               H0, H1, plog, syncw,
                                               labels_out, counts_out);
}